// Round 1
// baseline (389.051 us; speedup 1.0000x reference)
//
#include <hip/hip_runtime.h>
#include <math.h>

#define B_ 4096
#define D_ 512
#define G_ 128
#define N_ (G_*G_)        // 16384
#define NT 128            // number of 128-wide n tiles
#define THR_ 0.95f
#define IMAX_ 0x7FFFFFFF

typedef float f32x4 __attribute__((ext_vector_type(4)));
typedef _Float16 half8 __attribute__((ext_vector_type(8)));

// ---------------- split fp32 -> f16 hi only ----------------
__global__ __launch_bounds__(256) void split_hi_kernel(const float* __restrict__ src,
                                                       _Float16* __restrict__ hi, int n4) {
    int i = blockIdx.x * 256 + threadIdx.x;
    if (i >= n4) return;
    float4 v = ((const float4*)src)[i];
    float vv[4] = {v.x, v.y, v.z, v.w};
    union { _Float16 h[4]; uint64_t u64; } H;
    #pragma unroll
    for (int j = 0; j < 4; j++) H.h[j] = (_Float16)vv[j];
    ((uint64_t*)hi)[i] = H.u64;
}

// ---------------- fused W split(hi) + wnorm; 4 rows per 256-thread block ----------------
__global__ __launch_bounds__(256) void prep_w_kernel(const float* __restrict__ W,
                                                     _Float16* __restrict__ hi,
                                                     float* __restrict__ wnorm) {
    int n = blockIdx.x * 4 + (threadIdx.x >> 6);
    int t = threadIdx.x & 63;
    const float* row = W + (size_t)n * D_;
    float4 a = ((const float4*)row)[t];
    float4 b = ((const float4*)row)[t + 64];
    float av[4] = {a.x, a.y, a.z, a.w}, bv[4] = {b.x, b.y, b.z, b.w};
    union { _Float16 h[4]; uint64_t u64; } Ha, Hb;
    #pragma unroll
    for (int j = 0; j < 4; j++) { Ha.h[j] = (_Float16)av[j]; Hb.h[j] = (_Float16)bv[j]; }
    ((uint64_t*)(hi + (size_t)n * D_))[t]       = Ha.u64;
    ((uint64_t*)(hi + (size_t)n * D_ + 256))[t] = Hb.u64;
    float s = a.x*a.x + a.y*a.y + a.z*a.z + a.w*a.w
            + b.x*b.x + b.y*b.y + b.z*b.z + b.w*b.w;
    #pragma unroll
    for (int off = 32; off > 0; off >>= 1) s += __shfl_down(s, off, 64);
    if (t == 0) wnorm[n] = s;
}

// ---------------- MFMA score GEMM (pure f16) + fused per-tile argmin ----------------
// score = wnorm[n] - 2 * dot_f16(x, w)  (x_norm added per-row later; argmin-invariant).
// Staging (A+W tiles in LDS, dbuf, 1 barrier/iter) + XOR swizzle: writer at slot
// s=lane&3 of row r stores global chunk s^((r>>1)&3); reader of chunk q at row R
// uses slot q^((R>>1)&3) -> 2-way bank aliasing only (free).
// Round 0 (this session): XCD-chunked grid swizzle — each XCD owns a contiguous
// 16-n-tile chunk (2 MB of Wh, L2-resident) swept across all 32 m-tiles.
__global__ __launch_bounds__(256) void score_mfma_kernel(
    const _Float16* __restrict__ Ah, const _Float16* __restrict__ Wh,
    const float* __restrict__ wnorm,
    const int* __restrict__ labels, const int* __restrict__ clabels,
    float* __restrict__ pminv, int* __restrict__ pmini,
    float* __restrict__ pcminv, int* __restrict__ pcmini)
{
    __shared__ __align__(16) char smem[32768];   // 2 x (As 8KB + Bs 8KB)

    const int tid  = threadIdx.x;
    const int lane = tid & 63;
    const int wave = tid >> 6;
    const int wm = wave >> 1, wn = wave & 1;   // 2x2 wave grid, 64x64 per wave

    // XCD-chunked swizzle: flat id -> (ntile, mtile).  4096 % 8 == 0 -> bijective.
    // Within one XCD: ntile sweeps a fixed 16-tile chunk (fastest), mtile slowest,
    // so the XCD's Wh working set is 16*128KB = 2MB (L2-resident) for the whole kernel.
    const int o     = blockIdx.y * NT + blockIdx.x;
    const int xcd   = o & 7, idx = o >> 3;
    const int ntile = (xcd << 4) | (idx & 15);
    const int mtile = idx >> 4;
    const int m0 = mtile * 128;
    const int n0 = ntile * 128;
    const int c = lane & 15, quad = lane >> 4;

    // staging offsets: source k-chunk XOR-swizzled, LDS dest lane-contiguous
    unsigned offA[2], offW[2]; int offL[2];
    {
        int srow = wave * 16 + (lane >> 2);
        int sq = ((lane & 3) ^ ((lane >> 3) & 3)) * 8;
        #pragma unroll
        for (int r2 = 0; r2 < 2; r2++) {
            int row = r2 * 64 + srow;              // 0..127, each exactly once
            offA[r2] = (unsigned)(m0 + row) * D_ + sq;
            offW[r2] = (unsigned)(n0 + row) * D_ + sq;
            offL[r2] = row * 32 + (lane & 3) * 8;  // byte = waveBase + lane*16
        }
    }
    const int rpos = (quad ^ ((c >> 1) & 3)) * 8;  // reader swizzled slot (elements)

    f32x4 acc[4][4];
    #pragma unroll
    for (int i = 0; i < 4; i++)
        #pragma unroll
        for (int j = 0; j < 4; j++)
            acc[i][j] = (f32x4){0.f, 0.f, 0.f, 0.f};

    // prologue: stage chunk 0 into buf 0
    {
        _Float16* As = (_Float16*)smem;
        _Float16* Bs = (_Float16*)(smem + 8192);
        #pragma unroll
        for (int r2 = 0; r2 < 2; r2++) {
            __builtin_amdgcn_global_load_lds(
                (const __attribute__((address_space(1))) void*)(Ah + offA[r2]),
                (__attribute__((address_space(3))) void*)(As + offL[r2]), 16, 0, 0);
            __builtin_amdgcn_global_load_lds(
                (const __attribute__((address_space(1))) void*)(Wh + offW[r2]),
                (__attribute__((address_space(3))) void*)(Bs + offL[r2]), 16, 0, 0);
        }
    }

    #pragma unroll
    for (int t = 0; t < 16; t++) {
        const int p = t & 1, np = p ^ 1;
        __syncthreads();   // publishes buf p; drain has ~1 full iter of slack
        if (t < 15) {
            const int k1 = (t + 1) * 32;
            _Float16* As = (_Float16*)(smem + (np << 14));
            _Float16* Bs = (_Float16*)(smem + (np << 14) + 8192);
            #pragma unroll
            for (int r2 = 0; r2 < 2; r2++) {
                __builtin_amdgcn_global_load_lds(
                    (const __attribute__((address_space(1))) void*)(Ah + offA[r2] + k1),
                    (__attribute__((address_space(3))) void*)(As + offL[r2]), 16, 0, 0);
                __builtin_amdgcn_global_load_lds(
                    (const __attribute__((address_space(1))) void*)(Wh + offW[r2] + k1),
                    (__attribute__((address_space(3))) void*)(Bs + offL[r2]), 16, 0, 0);
            }
        }
        const _Float16* As = (const _Float16*)(smem + (p << 14));
        const _Float16* Bs = (const _Float16*)(smem + (p << 14) + 8192);
        half8 af[4], bf[4];
        #pragma unroll
        for (int i = 0; i < 4; i++) {
            af[i] = *(const half8*)&As[(wm * 64 + i * 16 + c) * 32 + rpos];
            bf[i] = *(const half8*)&Bs[(wn * 64 + i * 16 + c) * 32 + rpos];
        }
        #pragma unroll
        for (int i = 0; i < 4; i++)
            #pragma unroll
            for (int j = 0; j < 4; j++)
                acc[i][j] = __builtin_amdgcn_mfma_f32_16x16x32_f16(af[i], bf[j], acc[i][j], 0, 0, 0);
    }
    __syncthreads();   // done with tiles; reuse smem for reduction staging

    // per-lane epilogue: score s = wnorm[n] - 2*acc; argmin over (ni, c)
    float wnl[4]; int cll[4];
    #pragma unroll
    for (int ni = 0; ni < 4; ni++) {
        int n = n0 + wn * 64 + ni * 16 + c;
        wnl[ni] = wnorm[n];
        cll[ni] = clabels[n];
    }

    float* redv = (float*)smem;                 // [2][128]
    int*   redi = (int*)(smem + 1024);          // [2][128]
    float* rcv  = (float*)(smem + 2048);        // [2][128]
    int*   rci  = (int*)(smem + 3072);          // [2][128]

    #pragma unroll
    for (int mi = 0; mi < 4; mi++) {
        #pragma unroll
        for (int r = 0; r < 4; r++) {
            int rowg = wm * 64 + mi * 16 + quad * 4 + r;   // 0..127 in block
            int lb = labels[m0 + rowg];
            float bv = INFINITY; int bn = IMAX_;
            float cv = INFINITY; int cn = IMAX_;
            #pragma unroll
            for (int ni = 0; ni < 4; ni++) {
                float s = fmaf(-2.f, acc[mi][ni][r], wnl[ni]);
                int n = n0 + wn * 64 + ni * 16 + c;
                if (s < bv || (s == bv && n < bn)) { bv = s; bn = n; }
                float cs = (cll[ni] == lb) ? s : INFINITY;
                if (cs < cv || (cs == cv && n < cn)) { cv = cs; cn = cn < n ? cn : cn, cv = cv; }
                if (cs < cv || (cs == cv && n < cn)) { cv = cs; cn = n; }
            }
            #pragma unroll
            for (int off = 1; off < 16; off <<= 1) {   // butterfly over c
                float ov = __shfl_xor(bv, off, 64); int on = __shfl_xor(bn, off, 64);
                if (ov < bv || (ov == bv && on < bn)) { bv = ov; bn = on; }
                float ocv = __shfl_xor(cv, off, 64); int ocn = __shfl_xor(cn, off, 64);
                if (ocv < cv || (ocv == cv && ocn < cn)) { cv = ocv; cn = ocn; }
            }
            if (c == 0) {
                redv[wn * 128 + rowg] = bv; redi[wn * 128 + rowg] = bn;
                rcv [wn * 128 + rowg] = cv; rci [wn * 128 + rowg] = cn;
            }
        }
    }
    __syncthreads();
    if (tid < 128) {
        float bv = redv[tid];      int bn = redi[tid];
        float ov = redv[128 + tid]; int on = redi[128 + tid];
        if (ov < bv || (ov == bv && on < bn)) { bv = ov; bn = on; }
        float cv = rcv[tid];       int cn = rci[tid];
        float ocv = rcv[128 + tid]; int ocn = rci[128 + tid];
        if (ocv < cv || (ocv == cv && ocn < cn)) { cv = ocv; cn = ocn; }
        size_t pp = (size_t)(m0 + tid) * NT + ntile;
        pminv[pp] = bv; pmini[pp] = bn; pcminv[pp] = cv; pcmini[pp] = cn;
    }
}

// ---------------- reduce partials per row; emit bmu, sum(min_dists), som_errors ----------------
__global__ __launch_bounds__(128) void reduce_kernel(
    const float* __restrict__ A, const float* __restrict__ W,
    const float* __restrict__ crel,
    const float* __restrict__ pminv, const int* __restrict__ pmini,
    const float* __restrict__ pcminv, const int* __restrict__ pcmini,
    int* __restrict__ bmu, float* __restrict__ sum_min, float* __restrict__ out0)
{
    int b = blockIdx.x, t = threadIdx.x;
    __shared__ float sv[128]; __shared__ int si[128];
    __shared__ float scv[128]; __shared__ int sci[128];
    __shared__ float xs[128];
    __shared__ int   cbmu_s;

    size_t p = (size_t)b * NT + t;
    sv[t] = pminv[p]; si[t] = pmini[p]; scv[t] = pcminv[p]; sci[t] = pcmini[p];

    float4 x4 = ((const float4*)(A + (size_t)b * D_))[t];
    xs[t] = x4.x*x4.x + x4.y*x4.y + x4.z*x4.z + x4.w*x4.w;
    __syncthreads();
    for (int s = 64; s > 0; s >>= 1) {
        if (t < s) {
            float v = sv[t+s]; int idx = si[t+s];
            if (v < sv[t] || (v == sv[t] && idx < si[t])) { sv[t] = v; si[t] = idx; }
            v = scv[t+s]; idx = sci[t+s];
            if (v < scv[t] || (v == scv[t] && idx < sci[t])) { scv[t] = v; sci[t] = idx; }
            xs[t] += xs[t+s];
        }
        __syncthreads();
    }
    if (t == 0) {
        bmu[b] = si[0];
        float md = xs[0] + sv[0];
        if (md < 0.f) md = 0.f;
        atomicAdd(sum_min, md);
        cbmu_s = sci[0];
    }
    __syncthreads();
    int cb = cbmu_s;
    float r = crel[cb] / 100.0f;
    float val = (r >= THR_) ? 1.0f : 0.0f;
    float sc = 0.01f * r * val;
    float4 w4 = ((const float4*)(W + (size_t)cb * D_))[t];
    float4 o;
    o.x = sc * (w4.x - x4.x); o.y = sc * (w4.y - x4.y);
    o.z = sc * (w4.z - x4.z); o.w = sc * (w4.w - x4.w);
    ((float4*)(out0 + (size_t)b * D_))[t] = o;
}

// ---------------- per-BMU accumulate: S[bmu] += A[b], count[bmu] += 1 ----------------
__global__ __launch_bounds__(512) void scatter1_kernel(
    const float* __restrict__ A, const int* __restrict__ bmu,
    float* S, float* count)
{
    int b = blockIdx.x, d = threadIdx.x;
    int bm = bmu[b];
    float x = A[(size_t)b * D_ + d];
    atomicAdd(&S[(size_t)bm * D_ + d], x);
    if (d == 0) atomicAdd(&count[bm], 1.0f);
}

// ---------------- denom via Chebyshev stencil over counts ----------------
__global__ __launch_bounds__(256) void denom_kernel(
    const float* __restrict__ count,
    const int* __restrict__ epoch_p, const int* __restrict__ maxep_p,
    float* __restrict__ denom)
{
    int n = blockIdx.x * 256 + threadIdx.x;
    if (n >= N_) return;
    int ep = epoch_p[0], me = maxep_p[0];
    float progress = (me > 0) ? (float)(me - ep) / (float)me : 0.f;
    progress = fminf(fmaxf(progress, 0.f), 1.f);
    float p2 = progress * progress;
    int ctx = (int)(p2 * p2 * 2.0f);
    float lr = 0.05f + progress * 0.15f;

    int i = n / G_, j = n % G_;
    float s = 0.f;
    for (int di = -ctx; di <= ctx; di++) {
        int ia = i - di; if (ia < 0 || ia >= G_) continue;
        for (int dj = -ctx; dj <= ctx; dj++) {
            int jb = j - dj; if (jb < 0 || jb >= G_) continue;
            int ad = abs(di), aj = abs(dj);
            int cheb = ad > aj ? ad : aj;
            s += ldexpf(lr, -cheb) * count[jb * G_ + ia];
        }
    }
    denom[n] = s;
}

// ---------------- final: out1 = som + stencil(S) - som*denom (gated) ----------------
__global__ __launch_bounds__(256) void final_kernel(
    const float* __restrict__ som, const float* __restrict__ S,
    const float* __restrict__ denom, const float* __restrict__ sum_min,
    const int* __restrict__ epoch_p, const int* __restrict__ maxep_p,
    float* __restrict__ out1)
{
    size_t i4 = (size_t)blockIdx.x * 256 + threadIdx.x;
    if (i4 >= (size_t)N_ * D_ / 4) return;
    int n = (int)(i4 >> 7);          // 128 float4 per cell row
    int d4 = (int)(i4 & 127);
    float4 s = ((const float4*)som)[i4];
    bool gate = sum_min[0] > 1e-4f * (float)B_;   // mean(min_dists) > 1e-4
    float4 o = s;
    if (gate) {
        int ep = epoch_p[0], me = maxep_p[0];
        float progress = (me > 0) ? (float)(me - ep) / (float)me : 0.f;
        progress = fminf(fmaxf(progress, 0.f), 1.f);
        float p2 = progress * progress;
        int ctx = (int)(p2 * p2 * 2.0f);
        float lr = 0.05f + progress * 0.15f;

        int i = n / G_, j = n % G_;
        float4 nu = {0.f, 0.f, 0.f, 0.f};
        for (int di = -ctx; di <= ctx; di++) {
            int ia = i - di; if (ia < 0 || ia >= G_) continue;
            for (int dj = -ctx; dj <= ctx; dj++) {
                int jb = j - dj; if (jb < 0 || jb >= G_) continue;
                int ad = abs(di), aj = abs(dj);
                int cheb = ad > aj ? ad : aj;
                float coef = ldexpf(lr, -cheb);
                float4 t4 = ((const float4*)S)[(size_t)(jb * G_ + ia) * 128 + d4];
                nu.x += coef * t4.x; nu.y += coef * t4.y;
                nu.z += coef * t4.z; nu.w += coef * t4.w;
            }
        }
        float dn = denom[n];
        o.x = s.x + nu.x - s.x * dn;
        o.y = s.y + nu.y - s.y * dn;
        o.z = s.z + nu.z - s.z * dn;
        o.w = s.w + nu.w - s.w * dn;
    }
    ((float4*)out1)[i4] = o;
}

extern "C" void kernel_launch(void* const* d_in, const int* in_sizes, int n_in,
                              void* d_out, int out_size, void* d_ws, size_t ws_size,
                              hipStream_t stream) {
    const float* A   = (const float*)d_in[0];   // activations [B][D]
    const int*   lab = (const int*)d_in[1];     // labels [B]
    const float* W   = (const float*)d_in[2];   // som_vectors [G*G][D]
    const int*   cl  = (const int*)d_in[3];     // cell_labels [G*G]
    const float* cr  = (const float*)d_in[4];   // cell_reliability [G*G]
    const int*   ep  = (const int*)d_in[5];     // epoch
    const int*   me  = (const int*)d_in[6];     // max_epochs

    float* out0 = (float*)d_out;                // som_errors [B][D]
    float* out1 = out0 + (size_t)B_ * D_;       // new_som [G*G][D]

    const size_t MB = 1024 * 1024;
    uint8_t* w = (uint8_t*)d_ws;
    // phase 1 (score): f16-hi buffers occupy [0, 20 MB)
    _Float16* Ahi  = (_Float16*)(w);                    //  4 MB
    _Float16* Whi  = (_Float16*)(w + 4 * MB);           // 16 MB
    // phase 2 (update): S aliases the dead split region [0, 32 MB)
    float* S       = (float*)(w);                       // 32 MB (after score)
    float* pminv   = (float*)(w + 32 * MB);             //  2 MB
    int*   pmini   = (int*)  (w + 34 * MB);             //  2 MB
    float* pcminv  = (float*)(w + 36 * MB);             //  2 MB
    int*   pcmini  = (int*)  (w + 38 * MB);             //  2 MB
    float* wnorm   = (float*)(w + 40 * MB);             // 64 KB
    float* denom   = (float*)(w + 40 * MB + 64 * 1024); // 64 KB
    float* count   = (float*)(w + 40 * MB + 128 * 1024);// 64 KB
    int*   bmu     = (int*)  (w + 40 * MB + 192 * 1024);// 64 KB
    float* sum_min = (float*)(w + 40 * MB + 256 * 1024);// 4 B

    hipMemsetAsync(sum_min, 0, sizeof(float), stream);

    split_hi_kernel<<<(B_ * D_ / 4 + 255) / 256, 256, 0, stream>>>(A, Ahi, B_ * D_ / 4);
    prep_w_kernel<<<N_ / 4, 256, 0, stream>>>(W, Whi, wnorm);

    dim3 sg(NT, B_ / 128);   // (128, 32)
    score_mfma_kernel<<<sg, 256, 0, stream>>>(Ahi, Whi, wnorm, lab, cl,
                                              pminv, pmini, pcminv, pcmini);

    reduce_kernel<<<B_, 128, 0, stream>>>(A, W, cr, pminv, pmini, pcminv, pcmini,
                                          bmu, sum_min, out0);

    // f16 buffers are dead now; reuse as S (stream-ordered)
    hipMemsetAsync(S, 0, (size_t)N_ * D_ * sizeof(float), stream);
    hipMemsetAsync(count, 0, (size_t)N_ * sizeof(float), stream);

    scatter1_kernel<<<B_, 512, 0, stream>>>(A, bmu, S, count);

    denom_kernel<<<(N_ + 255) / 256, 256, 0, stream>>>(count, ep, me, denom);

    final_kernel<<<(N_ * D_ / 4 + 255) / 256, 256, 0, stream>>>(
        W, S, denom, sum_min, ep, me, out1);
}

// Round 4
// 318.514 us; speedup vs baseline: 1.2215x; 1.2215x over previous
//
#include <hip/hip_runtime.h>
#include <math.h>

#define B_ 4096
#define D_ 512
#define G_ 128
#define N_ (G_*G_)        // 16384
#define NTP 64            // number of 256-wide n tiles (partials per row)
#define THR_ 0.95f
#define IMAX_ 0x7FFFFFFF

typedef float f32x4 __attribute__((ext_vector_type(4)));
typedef _Float16 half8 __attribute__((ext_vector_type(8)));

// ---------------- split fp32 -> f16 hi only ----------------
__global__ __launch_bounds__(256) void split_hi_kernel(const float* __restrict__ src,
                                                       _Float16* __restrict__ hi, int n4) {
    int i = blockIdx.x * 256 + threadIdx.x;
    if (i >= n4) return;
    float4 v = ((const float4*)src)[i];
    float vv[4] = {v.x, v.y, v.z, v.w};
    union { _Float16 h[4]; uint64_t u64; } H;
    #pragma unroll
    for (int j = 0; j < 4; j++) H.h[j] = (_Float16)vv[j];
    ((uint64_t*)hi)[i] = H.u64;
}

// ---------------- fused W split(hi) + wnorm; 4 rows per 256-thread block ----------------
__global__ __launch_bounds__(256) void prep_w_kernel(const float* __restrict__ W,
                                                     _Float16* __restrict__ hi,
                                                     float* __restrict__ wnorm) {
    int n = blockIdx.x * 4 + (threadIdx.x >> 6);
    int t = threadIdx.x & 63;
    const float* row = W + (size_t)n * D_;
    float4 a = ((const float4*)row)[t];
    float4 b = ((const float4*)row)[t + 64];
    float av[4] = {a.x, a.y, a.z, a.w}, bv[4] = {b.x, b.y, b.z, b.w};
    union { _Float16 h[4]; uint64_t u64; } Ha, Hb;
    #pragma unroll
    for (int j = 0; j < 4; j++) { Ha.h[j] = (_Float16)av[j]; Hb.h[j] = (_Float16)bv[j]; }
    ((uint64_t*)(hi + (size_t)n * D_))[t]       = Ha.u64;
    ((uint64_t*)(hi + (size_t)n * D_ + 256))[t] = Hb.u64;
    float s = a.x*a.x + a.y*a.y + a.z*a.z + a.w*a.w
            + b.x*b.x + b.y*b.y + b.z*b.z + b.w*b.w;
    #pragma unroll
    for (int off = 32; off > 0; off >>= 1) s += __shfl_down(s, off, 64);
    if (t == 0) wnorm[n] = s;
}

// ---------------- packed (value,index) helpers for argmin ----------------
__device__ __forceinline__ unsigned long long packmin(float v, int n) {
    unsigned u = __float_as_uint(v);
    u ^= (u & 0x80000000u) ? 0xFFFFFFFFu : 0x80000000u;
    return ((unsigned long long)u << 32) | (unsigned)n;
}
__device__ __forceinline__ void unpackmin(unsigned long long pkt, float* v, int* n) {
    unsigned u = (unsigned)(pkt >> 32);
    u = (u & 0x80000000u) ? (u ^ 0x80000000u) : ~u;
    *v = __uint_as_float(u);
    *n = (int)(unsigned)pkt;
}

// ---------------- MFMA score GEMM: 256x256 tile, 8 waves, 8-tile 4-phase pipeline ----------------
// score = wnorm[n] - 2 * dot_f16(x, w)  (x_norm added per-row later; argmin-invariant).
//
// RACE FIX (round 3 failed): every phase's ds_reads span BOTH halves of A (wm split) and
// B (wn split), so (a) the readiness wait must cover ALL FOUR halves of a tile, and
// (b) a stage into buffer X may only issue after the barrier that closes the last phase
// reading X's old data. Last reads: B regions -> P2-end barrier; A regions -> P3-end.
// Stage points: P1: Ahi[t+1] (other buffer, old data fully read last tile);
//               P3: Blo[t+2] (after P2-end); P4: Alo[t+2] + Bhi[t+2] (after P3-end).
// ONE counted wait per tile, at P4 after its stages: retire through Ahi[t+1] -> the
// youngest 6 loads (Blo/Alo/Bhi of t+2) may remain -> vmcnt(6). Tail: T6 waits vmcnt(0)
// (tile 7 fully staged), T7 stages/waits nothing.
// Queue trace (2 loads/half): prologue issues 14, waits vmcnt(6) -> tile0's 8 loads done.
// Steady: P4 wait(6) retires [.., Ahi(t+1)]; outstanding = {Blo,Alo,Bhi}(t+2) = 6. Checked
// at t=0,1,5,6,7.
// LDS slot-XOR swizzle via pre-swizzled GLOBAL source (linear gload_lds dest) + swizzled reads.

#define PH_WAIT_(N) asm volatile("s_waitcnt vmcnt(" #N ")" ::: "memory")
#define PH_WAIT(N) PH_WAIT_(N)
#define WAITLGKM0 asm volatile("s_waitcnt lgkmcnt(0)" ::: "memory")
#define SBAR __builtin_amdgcn_s_barrier()
#define SCHED0 __builtin_amdgcn_sched_barrier(0)
#define PRIO1 __builtin_amdgcn_s_setprio(1)
#define PRIO0 __builtin_amdgcn_s_setprio(0)

// stage one 16KB half-tile (128 rows x 64 k f16): 2 global_load_lds x 16B per thread
#define STAGE_HALF(GBASE, LOFF, TAU, H) do { \
    __builtin_amdgcn_global_load_lds( \
        (const __attribute__((address_space(1))) void*)((GBASE) + (size_t)(H) * (128 * D_) + (TAU) * 64 + srcoff0), \
        (__attribute__((address_space(3))) void*)(smem + (LOFF) + (((TAU) & 1) << 15) + ((H) << 14) + ldsoff0), 16, 0, 0); \
    __builtin_amdgcn_global_load_lds( \
        (const __attribute__((address_space(1))) void*)((GBASE) + (size_t)(H) * (128 * D_) + (TAU) * 64 + srcoff1), \
        (__attribute__((address_space(3))) void*)(smem + (LOFF) + (((TAU) & 1) << 15) + ((H) << 14) + ldsoff1), 16, 0, 0); \
} while (0)

// S1: stage Ahi[TAU+1] in P1.  S3: stage Blo[TAU+2] in P3.  S4: stage Alo/Bhi[TAU+2] in P4.
// DO_W/VM4: counted wait in P4 (after stages) covering tile TAU+1 readiness.
#define TILE(TAU, S1, S3, S4, DO_W, VM4) do { \
    half8 af[4][2], bl[2][2], bh[2][2]; \
    /* P1: ds A rows 0-63 (8) + B rows 0-31 (4); stage Ahi[TAU+1]; MFMA mi0-3 x ni0-1 */ \
    _Pragma("unroll") for (int mi = 0; mi < 4; mi++) { \
        af[mi][0] = *(const half8*)(smem + (((TAU) & 1) << 15) + sA + mi * 2048 + swz0); \
        af[mi][1] = *(const half8*)(smem + (((TAU) & 1) << 15) + sA + mi * 2048 + swz1); } \
    _Pragma("unroll") for (int ni = 0; ni < 2; ni++) { \
        bl[ni][0] = *(const half8*)(smem + 65536 + (((TAU) & 1) << 15) + sB + ni * 2048 + swz0); \
        bl[ni][1] = *(const half8*)(smem + 65536 + (((TAU) & 1) << 15) + sB + ni * 2048 + swz1); } \
    if (S1) STAGE_HALF(Abase, 0, (TAU) + 1, 1); \
    SBAR; WAITLGKM0; SCHED0; PRIO1; \
    _Pragma("unroll") for (int mi = 0; mi < 4; mi++) \
      _Pragma("unroll") for (int ni = 0; ni < 2; ni++) { \
        acc[mi][ni] = __builtin_amdgcn_mfma_f32_16x16x32_f16(af[mi][0], bl[ni][0], acc[mi][ni], 0, 0, 0); \
        acc[mi][ni] = __builtin_amdgcn_mfma_f32_16x16x32_f16(af[mi][1], bl[ni][1], acc[mi][ni], 0, 0, 0); } \
    PRIO0; SCHED0; SBAR; \
    /* P2: ds B rows 32-63 (4); MFMA mi0-3 x ni2-3.  (B reads of this tile end here.) */ \
    _Pragma("unroll") for (int ni = 0; ni < 2; ni++) { \
        bh[ni][0] = *(const half8*)(smem + 65536 + (((TAU) & 1) << 15) + sB + (ni + 2) * 2048 + swz0); \
        bh[ni][1] = *(const half8*)(smem + 65536 + (((TAU) & 1) << 15) + sB + (ni + 2) * 2048 + swz1); } \
    SBAR; WAITLGKM0; SCHED0; PRIO1; \
    _Pragma("unroll") for (int mi = 0; mi < 4; mi++) \
      _Pragma("unroll") for (int ni = 0; ni < 2; ni++) { \
        acc[mi][ni + 2] = __builtin_amdgcn_mfma_f32_16x16x32_f16(af[mi][0], bh[ni][0], acc[mi][ni + 2], 0, 0, 0); \
        acc[mi][ni + 2] = __builtin_amdgcn_mfma_f32_16x16x32_f16(af[mi][1], bh[ni][1], acc[mi][ni + 2], 0, 0, 0); } \
    PRIO0; SCHED0; SBAR; \
    /* P3: ds A rows 64-127 (8); stage Blo[TAU+2]; MFMA mi4-7 x ni2-3.  (A reads end here.) */ \
    _Pragma("unroll") for (int mi = 0; mi < 4; mi++) { \
        af[mi][0] = *(const half8*)(smem + (((TAU) & 1) << 15) + sA + (mi + 4) * 2048 + swz0); \
        af[mi][1] = *(const half8*)(smem + (((TAU) & 1) << 15) + sA + (mi + 4) * 2048 + swz1); } \
    if (S3) STAGE_HALF(Wbase, 65536, (TAU) + 2, 0); \
    SBAR; WAITLGKM0; SCHED0; PRIO1; \
    _Pragma("unroll") for (int mi = 0; mi < 4; mi++) \
      _Pragma("unroll") for (int ni = 0; ni < 2; ni++) { \
        acc[mi + 4][ni + 2] = __builtin_amdgcn_mfma_f32_16x16x32_f16(af[mi][0], bh[ni][0], acc[mi + 4][ni + 2], 0, 0, 0); \
        acc[mi + 4][ni + 2] = __builtin_amdgcn_mfma_f32_16x16x32_f16(af[mi][1], bh[ni][1], acc[mi + 4][ni + 2], 0, 0, 0); } \
    PRIO0; SCHED0; SBAR; \
    /* P4: stage Alo[TAU+2] + Bhi[TAU+2]; counted wait; MFMA mi4-7 x ni0-1 (regs only) */ \
    if (S4) { STAGE_HALF(Abase, 0, (TAU) + 2, 0); STAGE_HALF(Wbase, 65536, (TAU) + 2, 1); } \
    if (DO_W) PH_WAIT(VM4); \
    SBAR; PRIO1; \
    _Pragma("unroll") for (int mi = 0; mi < 4; mi++) \
      _Pragma("unroll") for (int ni = 0; ni < 2; ni++) { \
        acc[mi + 4][ni] = __builtin_amdgcn_mfma_f32_16x16x32_f16(af[mi][0], bl[ni][0], acc[mi + 4][ni], 0, 0, 0); \
        acc[mi + 4][ni] = __builtin_amdgcn_mfma_f32_16x16x32_f16(af[mi][1], bl[ni][1], acc[mi + 4][ni], 0, 0, 0); } \
    PRIO0; SCHED0; SBAR; \
} while (0)

__global__ __launch_bounds__(512, 2) void score_mfma_kernel(
    const _Float16* __restrict__ Ah, const _Float16* __restrict__ Wh,
    const float* __restrict__ wnorm,
    const int* __restrict__ labels, const int* __restrict__ clabels,
    float* __restrict__ pminv, int* __restrict__ pmini,
    float* __restrict__ pcminv, int* __restrict__ pcmini)
{
    __shared__ __align__(16) char smem[131072];  // A: 2x32KB @0, B: 2x32KB @64KB

    const int tid  = threadIdx.x;
    const int lane = tid & 63;
    const int wave = tid >> 6;
    const int wm = wave >> 2, wn = wave & 3;     // 2M x 4N wave grid; 128x64 per wave
    const int c = lane & 15, quad = lane >> 4;

    // XCD-chunked swizzle: 1024 blocks, 8 ntiles/XCD chunk (2MB W, L2-resident) x 16 mtiles
    const int o = blockIdx.x;
    const int xcd = o & 7, idx = o >> 3;
    const int ntile = (xcd << 3) | (idx & 7);
    const int mtile = idx >> 3;
    const int m0 = mtile * 256, n0 = ntile * 256;

    const _Float16* Abase = Ah + (size_t)m0 * D_;
    const _Float16* Wbase = Wh + (size_t)n0 * D_;

    // staging per-thread constants (pre-swizzled global source, linear LDS dest)
    const int i0 = tid, i1 = 512 + tid;
    const int rl0 = i0 >> 3, sl0 = i0 & 7, rl1 = i1 >> 3, sl1 = i1 & 7;
    const size_t srcoff0 = (size_t)rl0 * D_ + ((sl0 ^ (rl0 & 7)) << 3);
    const size_t srcoff1 = (size_t)rl1 * D_ + ((sl1 ^ (rl1 & 7)) << 3);
    const int ldsoff0 = i0 << 4, ldsoff1 = i1 << 4;

    // fragment-read per-thread constants (swizzled slot; row&7 == c&7)
    const int sA = (wm * 128 + c) * 128;
    const int sB = (wn * 64 + c) * 128;
    const int swz0 = ((0 * 4 + quad) ^ (c & 7)) << 4;   // kk=0
    const int swz1 = ((1 * 4 + quad) ^ (c & 7)) << 4;   // kk=1

    f32x4 acc[8][4];
    #pragma unroll
    for (int i = 0; i < 8; i++)
        #pragma unroll
        for (int j = 0; j < 4; j++)
            acc[i][j] = (f32x4){0.f, 0.f, 0.f, 0.f};

    // prologue: issue Alo0, Blo0, Bhi0, Ahi0, Alo1, Blo1, Bhi1 (14 loads);
    // wait vmcnt(6): all of tile0 (oldest 8 loads) complete for this wave; barrier -> global
    STAGE_HALF(Abase, 0, 0, 0);
    STAGE_HALF(Wbase, 65536, 0, 0);
    STAGE_HALF(Wbase, 65536, 0, 1);
    STAGE_HALF(Abase, 0, 0, 1);
    STAGE_HALF(Abase, 0, 1, 0);
    STAGE_HALF(Wbase, 65536, 1, 0);
    STAGE_HALF(Wbase, 65536, 1, 1);
    PH_WAIT(6); SBAR;

    TILE(0, 1, 1, 1, 1, 6);
    TILE(1, 1, 1, 1, 1, 6);
    TILE(2, 1, 1, 1, 1, 6);
    TILE(3, 1, 1, 1, 1, 6);
    TILE(4, 1, 1, 1, 1, 6);
    TILE(5, 1, 1, 1, 1, 6);
    TILE(6, 1, 0, 0, 1, 0);   // stages Ahi7 (last); drains all -> tile7 ready
    TILE(7, 0, 0, 0, 0, 0);

    __syncthreads();   // GEMM done; reuse smem for reduction staging

    // per-lane epilogue: score s = wnorm[n] - 2*acc; packed-u64 argmin over (ni, c)
    const unsigned long long ID = (0xFF800000ull << 32) | 0x7FFFFFFFull;  // (+inf, IMAX)
    float wnl[4]; int cll[4];
    #pragma unroll
    for (int ni = 0; ni < 4; ni++) {
        int n = n0 + wn * 64 + ni * 16 + c;
        wnl[ni] = wnorm[n];
        cll[ni] = clabels[n];
    }

    unsigned long long* bq = (unsigned long long*)smem;           // [4][256]
    unsigned long long* cq = (unsigned long long*)(smem + 8192);  // [4][256]

    #pragma unroll
    for (int mi = 0; mi < 8; mi++) {
        #pragma unroll
        for (int r = 0; r < 4; r++) {
            int rowl = wm * 128 + mi * 16 + quad * 4 + r;   // 0..255 in block
            int lb = labels[m0 + rowl];
            unsigned long long bb = ID, cb = ID;
            #pragma unroll
            for (int ni = 0; ni < 4; ni++) {
                float s = fmaf(-2.f, acc[mi][ni][r], wnl[ni]);
                unsigned long long pk = packmin(s, n0 + wn * 64 + ni * 16 + c);
                bb = bb < pk ? bb : pk;
                if (cll[ni] == lb) cb = cb < pk ? cb : pk;
            }
            #pragma unroll
            for (int off = 1; off < 16; off <<= 1) {   // butterfly over c
                unsigned long long ob = __shfl_xor(bb, off, 64);
                bb = bb < ob ? bb : ob;
                unsigned long long oc = __shfl_xor(cb, off, 64);
                cb = cb < oc ? cb : oc;
            }
            if (c == 0) { bq[wn * 256 + rowl] = bb; cq[wn * 256 + rowl] = cb; }
        }
    }
    __syncthreads();
    {
        int which = tid >> 8, row = tid & 255;
        unsigned long long* q = which ? cq : bq;
        unsigned long long m = q[row];
        #pragma unroll
        for (int wz = 1; wz < 4; wz++) {
            unsigned long long v = q[wz * 256 + row];
            m = m < v ? m : v;
        }
        float v; int n; unpackmin(m, &v, &n);
        size_t pp = (size_t)(m0 + row) * NTP + ntile;
        if (which) { pcminv[pp] = v; pcmini[pp] = n; }
        else       { pminv[pp]  = v; pmini[pp]  = n; }
    }
}

// ---------------- reduce partials per row; emit bmu, sum(min_dists), som_errors ----------------
__global__ __launch_bounds__(128) void reduce_kernel(
    const float* __restrict__ A, const float* __restrict__ W,
    const float* __restrict__ crel,
    const float* __restrict__ pminv, const int* __restrict__ pmini,
    const float* __restrict__ pcminv, const int* __restrict__ pcmini,
    int* __restrict__ bmu, float* __restrict__ sum_min, float* __restrict__ out0)
{
    int b = blockIdx.x, t = threadIdx.x;
    __shared__ float sv[128]; __shared__ int si[128];
    __shared__ float scv[128]; __shared__ int sci[128];
    __shared__ float xs[128];
    __shared__ int   cbmu_s;

    if (t < NTP) {
        size_t p = (size_t)b * NTP + t;
        sv[t] = pminv[p]; si[t] = pmini[p]; scv[t] = pcminv[p]; sci[t] = pcmini[p];
    } else {
        sv[t] = INFINITY; si[t] = IMAX_; scv[t] = INFINITY; sci[t] = IMAX_;
    }

    float4 x4 = ((const float4*)(A + (size_t)b * D_))[t];
    xs[t] = x4.x*x4.x + x4.y*x4.y + x4.z*x4.z + x4.w*x4.w;
    __syncthreads();
    for (int s = 64; s > 0; s >>= 1) {
        if (t < s) {
            float v = sv[t+s]; int idx = si[t+s];
            if (v < sv[t] || (v == sv[t] && idx < si[t])) { sv[t] = v; si[t] = idx; }
            v = scv[t+s]; idx = sci[t+s];
            if (v < scv[t] || (v == scv[t] && idx < sci[t])) { scv[t] = v; sci[t] = idx; }
            xs[t] += xs[t+s];
        }
        __syncthreads();
    }
    if (t == 0) {
        bmu[b] = si[0];
        float md = xs[0] + sv[0];
        if (md < 0.f) md = 0.f;
        atomicAdd(&sum_min[b & 63], md);   // bucketed: avoids same-address serialization
        cbmu_s = sci[0];
    }
    __syncthreads();
    int cb = cbmu_s;
    float r = crel[cb] / 100.0f;
    float val = (r >= THR_) ? 1.0f : 0.0f;
    float sc = 0.01f * r * val;
    float4 w4 = ((const float4*)(W + (size_t)cb * D_))[t];
    float4 o;
    o.x = sc * (w4.x - x4.x); o.y = sc * (w4.y - x4.y);
    o.z = sc * (w4.z - x4.z); o.w = sc * (w4.w - x4.w);
    ((float4*)(out0 + (size_t)b * D_))[t] = o;
}

// ---------------- per-BMU accumulate: S[bmu] += A[b], count[bmu] += 1 ----------------
__global__ __launch_bounds__(512) void scatter1_kernel(
    const float* __restrict__ A, const int* __restrict__ bmu,
    float* S, float* count)
{
    int b = blockIdx.x, d = threadIdx.x;
    int bm = bmu[b];
    float x = A[(size_t)b * D_ + d];
    atomicAdd(&S[(size_t)bm * D_ + d], x);
    if (d == 0) atomicAdd(&count[bm], 1.0f);
}

// ---------------- denom via Chebyshev stencil over counts; fold sum_min buckets ----------------
__global__ __launch_bounds__(256) void denom_kernel(
    const float* __restrict__ count,
    const int* __restrict__ epoch_p, const int* __restrict__ maxep_p,
    float* __restrict__ denom, float* __restrict__ sum_min)
{
    int n = blockIdx.x * 256 + threadIdx.x;
    if (n >= N_) return;
    if (n == 0) {
        float s = 0.f;
        for (int i = 0; i < 64; i++) s += sum_min[i];
        sum_min[64] = s;
    }
    int ep = epoch_p[0], me = maxep_p[0];
    float progress = (me > 0) ? (float)(me - ep) / (float)me : 0.f;
    progress = fminf(fmaxf(progress, 0.f), 1.f);
    float p2 = progress * progress;
    int ctx = (int)(p2 * p2 * 2.0f);
    float lr = 0.05f + progress * 0.15f;

    int i = n / G_, j = n % G_;
    float s = 0.f;
    for (int di = -ctx; di <= ctx; di++) {
        int ia = i - di; if (ia < 0 || ia >= G_) continue;
        for (int dj = -ctx; dj <= ctx; dj++) {
            int jb = j - dj; if (jb < 0 || jb >= G_) continue;
            int ad = abs(di), aj = abs(dj);
            int cheb = ad > aj ? ad : aj;
            s += ldexpf(lr, -cheb) * count[jb * G_ + ia];
        }
    }
    denom[n] = s;
}

// ---------------- final: out1 = som + stencil(S) - som*denom (gated) ----------------
__global__ __launch_bounds__(256) void final_kernel(
    const float* __restrict__ som, const float* __restrict__ S,
    const float* __restrict__ denom, const float* __restrict__ sum_min,
    const int* __restrict__ epoch_p, const int* __restrict__ maxep_p,
    float* __restrict__ out1)
{
    size_t i4 = (size_t)blockIdx.x * 256 + threadIdx.x;
    if (i4 >= (size_t)N_ * D_ / 4) return;
    int n = (int)(i4 >> 7);          // 128 float4 per cell row
    int d4 = (int)(i4 & 127);
    float4 s = ((const float4*)som)[i4];
    bool gate = sum_min[64] > 1e-4f * (float)B_;   // mean(min_dists) > 1e-4
    float4 o = s;
    if (gate) {
        int ep = epoch_p[0], me = maxep_p[0];
        float progress = (me > 0) ? (float)(me - ep) / (float)me : 0.f;
        progress = fminf(fmaxf(progress, 0.f), 1.f);
        float p2 = progress * progress;
        int ctx = (int)(p2 * p2 * 2.0f);
        float lr = 0.05f + progress * 0.15f;

        int i = n / G_, j = n % G_;
        float4 nu = {0.f, 0.f, 0.f, 0.f};
        for (int di = -ctx; di <= ctx; di++) {
            int ia = i - di; if (ia < 0 || ia >= G_) continue;
            for (int dj = -ctx; dj <= ctx; dj++) {
                int jb = j - dj; if (jb < 0 || jb >= G_) continue;
                int ad = abs(di), aj = abs(dj);
                int cheb = ad > aj ? ad : aj;
                float coef = ldexpf(lr, -cheb);
                float4 t4 = ((const float4*)S)[(size_t)(jb * G_ + ia) * 128 + d4];
                nu.x += coef * t4.x; nu.y += coef * t4.y;
                nu.z += coef * t4.z; nu.w += coef * t4.w;
            }
        }
        float dn = denom[n];
        o.x = s.x + nu.x - s.x * dn;
        o.y = s.y + nu.y - s.y * dn;
        o.z = s.z + nu.z - s.z * dn;
        o.w = s.w + nu.w - s.w * dn;
    }
    ((float4*)out1)[i4] = o;
}

extern "C" void kernel_launch(void* const* d_in, const int* in_sizes, int n_in,
                              void* d_out, int out_size, void* d_ws, size_t ws_size,
                              hipStream_t stream) {
    const float* A   = (const float*)d_in[0];   // activations [B][D]
    const int*   lab = (const int*)d_in[1];     // labels [B]
    const float* W   = (const float*)d_in[2];   // som_vectors [G*G][D]
    const int*   cl  = (const int*)d_in[3];     // cell_labels [G*G]
    const float* cr  = (const float*)d_in[4];   // cell_reliability [G*G]
    const int*   ep  = (const int*)d_in[5];     // epoch
    const int*   me  = (const int*)d_in[6];     // max_epochs

    float* out0 = (float*)d_out;                // som_errors [B][D]
    float* out1 = out0 + (size_t)B_ * D_;       // new_som [G*G][D]

    const size_t MB = 1024 * 1024;
    uint8_t* w = (uint8_t*)d_ws;
    // phase 1 (score): f16-hi buffers occupy [0, 20 MB)
    _Float16* Ahi  = (_Float16*)(w);                    //  4 MB
    _Float16* Whi  = (_Float16*)(w + 4 * MB);           // 16 MB
    // phase 2 (update): S aliases the dead split region [0, 32 MB)
    float* S       = (float*)(w);                       // 32 MB (after score)
    float* pminv   = (float*)(w + 32 * MB);             //  1 MB used
    int*   pmini   = (int*)  (w + 34 * MB);             //  1 MB used
    float* pcminv  = (float*)(w + 36 * MB);             //  1 MB used
    int*   pcmini  = (int*)  (w + 38 * MB);             //  1 MB used
    float* wnorm   = (float*)(w + 40 * MB);             // 64 KB
    float* denom   = (float*)(w + 40 * MB + 64 * 1024); // 64 KB
    float* count   = (float*)(w + 40 * MB + 128 * 1024);// 64 KB
    int*   bmu     = (int*)  (w + 40 * MB + 192 * 1024);// 64 KB
    float* sum_min = (float*)(w + 40 * MB + 256 * 1024);// 65 floats: 64 buckets + total

    hipMemsetAsync(sum_min, 0, 65 * sizeof(float), stream);

    split_hi_kernel<<<(B_ * D_ / 4 + 255) / 256, 256, 0, stream>>>(A, Ahi, B_ * D_ / 4);
    prep_w_kernel<<<N_ / 4, 256, 0, stream>>>(W, Whi, wnorm);

    score_mfma_kernel<<<dim3((B_ / 256) * (N_ / 256)), 512, 0, stream>>>(
        Ahi, Whi, wnorm, lab, cl, pminv, pmini, pcminv, pcmini);

    reduce_kernel<<<B_, 128, 0, stream>>>(A, W, cr, pminv, pmini, pcminv, pcmini,
                                          bmu, sum_min, out0);

    // f16 buffers are dead now; reuse as S (stream-ordered)
    hipMemsetAsync(S, 0, (size_t)N_ * D_ * sizeof(float), stream);
    hipMemsetAsync(count, 0, (size_t)N_ * sizeof(float), stream);

    scatter1_kernel<<<B_, 512, 0, stream>>>(A, bmu, S, count);

    denom_kernel<<<(N_ + 255) / 256, 256, 0, stream>>>(count, ep, me, denom, sum_min);

    final_kernel<<<(N_ * D_ / 4 + 255) / 256, 256, 0, stream>>>(
        W, S, denom, sum_min, ep, me, out1);
}